// Round 7
// baseline (313.018 us; speedup 1.0000x reference)
//
#include <hip/hip_runtime.h>

#define NB   4
#define H_IN 14
#define W_IN 14
#define FIN  32
#define DI   8
#define F    32
#define C    288   // 3*3*32
#define DO   16
#define HO   12
#define WO   12
#define NPOS (NB*HO*WO)   // 576
#define EPS  1e-7f

#define GP   8             // positions per block
#define NPG  (NPOS/GP)     // 72

#define W2_BYTES   ((size_t)F*C*DO*DI*4)       // 4,718,592
#define CENT_BYTES ((size_t)NPOS*F*DO*4)       // 1,179,648 per chunk-slice

__device__ __forceinline__ float dot8f(const float4 w0, const float4 w1,
                                       const float4 p0, const float4 p1) {
    return w0.x*p0.x + w0.y*p0.y + w0.z*p0.z + w0.w*p0.w
         + w1.x*p1.x + w1.y*p1.y + w1.z*p1.z + w1.w*p1.w;
}

// XCD-locality mapping: consecutive blocks round-robin across 8 XCDs (%8
// heuristic). Make ch a function of (blk & 7) so each XCD touches only
// 1-2 W2 c-chunks -> per-XCD L2 working set ~0.3-0.6 MB instead of 4.7 MB.
template<int CHN>
__device__ __forceinline__ void map_blk(int blk, int& ch, int& pg) {
    if (CHN == 16)      { ch = 2*(blk & 7) + ((blk >> 3) & 1); pg = blk >> 4; }
    else if (CHN == 8)  { ch = blk & 7;  pg = blk >> 3; }
    else                { ch = blk & 3;  pg = blk >> 2; }   // CHN == 4
}

// ---- transpose W[f][c][o][i] -> W2[c][o][f][i] (coalesced writes) -------------
__global__ __launch_bounds__(256) void kernT(const float* __restrict__ Wt,
                                             float* __restrict__ W2) {
    const int idx4 = blockIdx.x*256 + threadIdx.x;   // output float4 index
    const int i2 = idx4 & 1;
    const int f  = (idx4 >> 1) & 31;
    const int o  = (idx4 >> 6) & 15;
    const int c  = idx4 >> 10;
    ((float4*)W2)[idx4] = ((const float4*)Wt)[((size_t)(f*C + c)*DO + o)*2 + i2];
}

// ---- kern1: cent1 partials over a c-chunk -> part1[ch][pos][f][o] -------------
template<int CHN>
__global__ __launch_bounds__(256, 4) void kern1t(const float* __restrict__ x,
                                                 const float* __restrict__ W2,
                                                 float* __restrict__ part1)
{
    constexpr int CC = C / CHN;
    const int tid = threadIdx.x;
    const int f = tid & 31, p = tid >> 5;
    int ch, pg;
    map_blk<CHN>(blockIdx.x, ch, pg);
    const int pos = pg*GP + p;
    const int b = pos/(HO*WO), rem = pos%(HO*WO), ho = rem/WO, wo = rem%WO;

    const float4* W2f4 = (const float4*)W2;
    float acc[DO];
    #pragma unroll
    for (int o = 0; o < DO; ++o) acc[o] = 0.f;

    const int c0 = ch*CC;
    #pragma unroll 1
    for (int c = c0; c < c0 + CC; ++c) {
        const int slab = c >> 5, fin = c & 31;
        const int kh = slab/3, kw = slab%3;
        const float4* px = (const float4*)(x + (size_t)(((b*H_IN + ho+kh)*W_IN + wo+kw)*FIN + fin)*DI);
        const float4 p0 = px[0], p1 = px[1];
        const float4* wb = W2f4 + (size_t)c*(DO*F*2) + f*2;
        // o-half 0: batch 16 loads, then 64 FMAs
        {
            float4 w[16];
            #pragma unroll
            for (int o = 0; o < 8; ++o) { w[2*o] = wb[o*64]; w[2*o+1] = wb[o*64+1]; }
            #pragma unroll
            for (int o = 0; o < 8; ++o) acc[o] += dot8f(w[2*o], w[2*o+1], p0, p1);
        }
        // o-half 1
        {
            float4 w[16];
            #pragma unroll
            for (int o = 0; o < 8; ++o) { w[2*o] = wb[(o+8)*64]; w[2*o+1] = wb[(o+8)*64+1]; }
            #pragma unroll
            for (int o = 0; o < 8; ++o) acc[8+o] += dot8f(w[2*o], w[2*o+1], p0, p1);
        }
    }
    float4* dst = (float4*)(part1 + ((size_t)(ch*NPOS + pos)*F + f)*DO);
    dst[0] = make_float4(acc[0],  acc[1],  acc[2],  acc[3]);
    dst[1] = make_float4(acc[4],  acc[5],  acc[6],  acc[7]);
    dst[2] = make_float4(acc[8],  acc[9],  acc[10], acc[11]);
    dst[3] = make_float4(acc[12], acc[13], acc[14], acc[15]);
}

// ---- kern2: out1 from part1-reduce; per-c pred/agr/softmax_f; cent2 partials. --
template<int CH1N, int CH2N>
__global__ __launch_bounds__(256, 3) void kern2t(const float* __restrict__ x,
                                                 const float* __restrict__ W2,
                                                 const float* __restrict__ part1,
                                                 float* __restrict__ part2)
{
    constexpr int CC = C / CH2N;
    const int tid = threadIdx.x;
    const int f = tid & 31, p = tid >> 5;
    int ch, pg;
    map_blk<CH2N>(blockIdx.x, ch, pg);
    const int pos = pg*GP + p;
    const int b = pos/(HO*WO), rem = pos%(HO*WO), ho = rem/WO, wo = rem%WO;

    // reduce cent1 partials (in-thread), squash -> out1
    float out1[DO];
    {
        #pragma unroll
        for (int o = 0; o < DO; ++o) out1[o] = 0.f;
        #pragma unroll
        for (int k = 0; k < CH1N; ++k) {
            const float4* s = (const float4*)(part1 + ((size_t)(k*NPOS + pos)*F + f)*DO);
            #pragma unroll
            for (int q = 0; q < 4; ++q) {
                const float4 v = s[q];
                out1[q*4+0] += v.x; out1[q*4+1] += v.y;
                out1[q*4+2] += v.z; out1[q*4+3] += v.w;
            }
        }
        float sn = 0.f;
        #pragma unroll
        for (int o = 0; o < DO; ++o) { out1[o] *= (1.f/32.f); sn += out1[o]*out1[o]; }
        const float sc1 = (sn/(1.f + sn)) * rsqrtf(sn + EPS);
        #pragma unroll
        for (int o = 0; o < DO; ++o) out1[o] *= sc1;
    }

    const float4* W2f4 = (const float4*)W2;
    float cent2[DO];
    #pragma unroll
    for (int o = 0; o < DO; ++o) cent2[o] = 0.f;

    const int c0 = ch*CC;
    #pragma unroll 1
    for (int c = c0; c < c0 + CC; ++c) {
        const int slab = c >> 5, fin = c & 31;
        const int kh = slab/3, kw = slab%3;
        const float4* px = (const float4*)(x + (size_t)(((b*H_IN + ho+kh)*W_IN + wo+kw)*FIN + fin)*DI);
        const float4 p0 = px[0], p1 = px[1];
        const float4* wb = W2f4 + (size_t)c*(DO*F*2) + f*2;
        float pred[DO];
        {
            float4 w[16];
            #pragma unroll
            for (int o = 0; o < 8; ++o) { w[2*o] = wb[o*64]; w[2*o+1] = wb[o*64+1]; }
            #pragma unroll
            for (int o = 0; o < 8; ++o) pred[o] = dot8f(w[2*o], w[2*o+1], p0, p1);
        }
        {
            float4 w[16];
            #pragma unroll
            for (int o = 0; o < 8; ++o) { w[2*o] = wb[(o+8)*64]; w[2*o+1] = wb[(o+8)*64+1]; }
            #pragma unroll
            for (int o = 0; o < 8; ++o) pred[8+o] = dot8f(w[2*o], w[2*o+1], p0, p1);
        }
        float agr = 0.f;
        #pragma unroll
        for (int o = 0; o < DO; ++o) agr += pred[o]*out1[o];
        // softmax over the 32 f-lanes (xor masks <32 stay within each f-group)
        float m = agr;
        m = fmaxf(m, __shfl_xor(m, 1));
        m = fmaxf(m, __shfl_xor(m, 2));
        m = fmaxf(m, __shfl_xor(m, 4));
        m = fmaxf(m, __shfl_xor(m, 8));
        m = fmaxf(m, __shfl_xor(m, 16));
        const float e = __expf(agr - m);
        float s = e;
        s += __shfl_xor(s, 1);
        s += __shfl_xor(s, 2);
        s += __shfl_xor(s, 4);
        s += __shfl_xor(s, 8);
        s += __shfl_xor(s, 16);
        const float cc = e / s;
        #pragma unroll
        for (int o = 0; o < DO; ++o) cent2[o] += cc*pred[o];
    }
    float4* dst = (float4*)(part2 + ((size_t)(ch*NPOS + pos)*F + f)*DO);
    dst[0] = make_float4(cent2[0],  cent2[1],  cent2[2],  cent2[3]);
    dst[1] = make_float4(cent2[4],  cent2[5],  cent2[6],  cent2[7]);
    dst[2] = make_float4(cent2[8],  cent2[9],  cent2[10], cent2[11]);
    dst[3] = make_float4(cent2[12], cent2[13], cent2[14], cent2[15]);
}

// ---- kern3: reduce cent2 partials, squash, store. -----------------------------
template<int CH2N>
__global__ __launch_bounds__(256) void kern3t(const float* __restrict__ part2,
                                              float* __restrict__ out)
{
    const int tid = threadIdx.x;
    const int f = tid & 31, p = tid >> 5;
    const int pos = blockIdx.x*GP + p;

    float cent[DO];
    #pragma unroll
    for (int o = 0; o < DO; ++o) cent[o] = 0.f;
    #pragma unroll
    for (int k = 0; k < CH2N; ++k) {
        const float4* s = (const float4*)(part2 + ((size_t)(k*NPOS + pos)*F + f)*DO);
        #pragma unroll
        for (int q = 0; q < 4; ++q) {
            const float4 v = s[q];
            cent[q*4+0] += v.x; cent[q*4+1] += v.y;
            cent[q*4+2] += v.z; cent[q*4+3] += v.w;
        }
    }
    float sn = 0.f;
    #pragma unroll
    for (int o = 0; o < DO; ++o) sn += cent[o]*cent[o];
    const float sc = (sn/(1.f + sn)) * rsqrtf(sn + EPS);
    float4* dst = (float4*)(out + ((size_t)pos*F + f)*DO);
    dst[0] = make_float4(cent[0]*sc,  cent[1]*sc,  cent[2]*sc,  cent[3]*sc);
    dst[1] = make_float4(cent[4]*sc,  cent[5]*sc,  cent[6]*sc,  cent[7]*sc);
    dst[2] = make_float4(cent[8]*sc,  cent[9]*sc,  cent[10]*sc, cent[11]*sc);
    dst[3] = make_float4(cent[12]*sc, cent[13]*sc, cent[14]*sc, cent[15]*sc);
}

// -------- fp32 single-kernel fallback (if ws too small) ------------------------
__device__ __forceinline__ float dot8(const float4* __restrict__ w,
                                      const float4 p0, const float4 p1) {
    float4 a = w[0], b = w[1];
    return a.x*p0.x + a.y*p0.y + a.z*p0.z + a.w*p0.w
         + b.x*p1.x + b.y*p1.y + b.z*p1.z + b.w*p1.w;
}

__global__ __launch_bounds__(256) void capsule_kernel_f32(
    const float* __restrict__ x, const float* __restrict__ Wt,
    float* __restrict__ out)
{
    __shared__ float patch[C*DI];
    __shared__ float cent[F*DO];
    __shared__ float out1[F*DO];
    __shared__ float agr[F*C];
    __shared__ float scale_s[F];

    const int tid = threadIdx.x;
    const int pos = blockIdx.x;
    const int b   = pos / (HO*WO);
    const int rem = pos % (HO*WO);
    const int ho  = rem / WO;
    const int wo  = rem % WO;

    #pragma unroll
    for (int slab = 0; slab < 9; ++slab) {
        const int kh = slab / 3, kw = slab % 3;
        const float* src = x + (((b*H_IN + ho + kh)*W_IN + (wo + kw))*FIN)*DI;
        patch[slab*256 + tid] = src[tid];
    }
    __syncthreads();

    const float4* pv = (const float4*)patch;

    {
        const int fo0 = tid, fo1 = tid + 256;
        const int f0 = fo0 >> 4, o0 = fo0 & 15;
        const int f1 = fo1 >> 4, o1 = fo1 & 15;
        float acc0 = 0.f, acc1 = 0.f;
        for (int c = 0; c < C; ++c) {
            const float4 p0 = pv[c*2], p1 = pv[c*2+1];
            acc0 += dot8((const float4*)(Wt + ((f0*C + c)*DO + o0)*DI), p0, p1);
            acc1 += dot8((const float4*)(Wt + ((f1*C + c)*DO + o1)*DI), p0, p1);
        }
        cent[fo0] = acc0 * (1.f/32.f);
        cent[fo1] = acc1 * (1.f/32.f);
    }
    __syncthreads();

    if (tid < F) {
        float sn = 0.f;
        #pragma unroll
        for (int o = 0; o < DO; ++o) { float v = cent[tid*DO + o]; sn += v*v; }
        const float sc = (sn/(1.f + sn)) * rsqrtf(sn + EPS);
        #pragma unroll
        for (int o = 0; o < DO; ++o) out1[tid*DO + o] = cent[tid*DO + o] * sc;
    }
    __syncthreads();

    #pragma unroll 1
    for (int r = 0; r < (F*C)/256; ++r) {
        const int pp = tid + 256*r;
        const int f = pp / C, c = pp % C;
        const float4* wrow = (const float4*)(Wt + (f*C + c)*DO*DI);
        const float4 p0 = pv[c*2], p1 = pv[c*2+1];
        float a = 0.f;
        #pragma unroll
        for (int o = 0; o < DO; ++o) a += dot8(wrow + o*2, p0, p1) * out1[f*DO + o];
        agr[pp] = a;
    }
    __syncthreads();

    for (int c = tid; c < C; c += 256) {
        float m = -1e30f;
        #pragma unroll
        for (int f = 0; f < F; ++f) m = fmaxf(m, agr[f*C + c]);
        float s = 0.f;
        #pragma unroll
        for (int f = 0; f < F; ++f) {
            const float e = __expf(agr[f*C + c] - m);
            agr[f*C + c] = e; s += e;
        }
        const float inv = 1.f / s;
        #pragma unroll
        for (int f = 0; f < F; ++f) agr[f*C + c] *= inv;
    }
    __syncthreads();

    {
        const int fo0 = tid, fo1 = tid + 256;
        const int f0 = fo0 >> 4, o0 = fo0 & 15;
        const int f1 = fo1 >> 4, o1 = fo1 & 15;
        float acc0 = 0.f, acc1 = 0.f;
        for (int c = 0; c < C; ++c) {
            const float4 p0 = pv[c*2], p1 = pv[c*2+1];
            acc0 += agr[f0*C + c] * dot8((const float4*)(Wt + ((f0*C + c)*DO + o0)*DI), p0, p1);
            acc1 += agr[f1*C + c] * dot8((const float4*)(Wt + ((f1*C + c)*DO + o1)*DI), p0, p1);
        }
        cent[fo0] = acc0;
        cent[fo1] = acc1;
    }
    __syncthreads();

    if (tid < F) {
        float sn = 0.f;
        #pragma unroll
        for (int o = 0; o < DO; ++o) { float v = cent[tid*DO + o]; sn += v*v; }
        scale_s[tid] = (sn/(1.f + sn)) * rsqrtf(sn + EPS);
    }
    __syncthreads();

    out[pos*(F*DO) + tid]       = cent[tid]       * scale_s[tid >> 4];
    out[pos*(F*DO) + tid + 256] = cent[tid + 256] * scale_s[(tid >> 4) + 16];
}

extern "C" void kernel_launch(void* const* d_in, const int* in_sizes, int n_in,
                              void* d_out, int out_size, void* d_ws, size_t ws_size,
                              hipStream_t stream) {
    const float* x  = (const float*)d_in[0];
    const float* Wt = (const float*)d_in[1];
    float* out = (float*)d_out;

    float* W2 = (float*)d_ws;

    // ladder on workspace size: CH1/CH2 = 16/16 -> 16/8 -> 4/8 -> fallback
    if (ws_size >= W2_BYTES + 16*CENT_BYTES + 16*CENT_BYTES) {
        float* part1 = (float*)((char*)d_ws + W2_BYTES);
        float* part2 = (float*)((char*)d_ws + W2_BYTES + 16*CENT_BYTES);
        kernT<<<(F*C*DO*DI)/4/256, 256, 0, stream>>>(Wt, W2);
        kern1t<16><<<16*NPG, 256, 0, stream>>>(x, W2, part1);            // 1152 blocks
        kern2t<16,16><<<16*NPG, 256, 0, stream>>>(x, W2, part1, part2);  // 1152
        kern3t<16><<<NPG, 256, 0, stream>>>(part2, out);
    } else if (ws_size >= W2_BYTES + 16*CENT_BYTES + 8*CENT_BYTES) {
        float* part1 = (float*)((char*)d_ws + W2_BYTES);
        float* part2 = (float*)((char*)d_ws + W2_BYTES + 16*CENT_BYTES);
        kernT<<<(F*C*DO*DI)/4/256, 256, 0, stream>>>(Wt, W2);
        kern1t<16><<<16*NPG, 256, 0, stream>>>(x, W2, part1);
        kern2t<16,8><<<8*NPG, 256, 0, stream>>>(x, W2, part1, part2);
        kern3t<8><<<NPG, 256, 0, stream>>>(part2, out);
    } else if (ws_size >= W2_BYTES + 4*CENT_BYTES + 8*CENT_BYTES) {
        float* part1 = (float*)((char*)d_ws + W2_BYTES);
        float* part2 = (float*)((char*)d_ws + W2_BYTES + 4*CENT_BYTES);
        kernT<<<(F*C*DO*DI)/4/256, 256, 0, stream>>>(Wt, W2);
        kern1t<4><<<4*NPG, 256, 0, stream>>>(x, W2, part1);
        kern2t<4,8><<<8*NPG, 256, 0, stream>>>(x, W2, part1, part2);
        kern3t<8><<<NPG, 256, 0, stream>>>(part2, out);
    } else {
        capsule_kernel_f32<<<NPOS, 256, 0, stream>>>(x, Wt, out);
    }
}

// Round 8
// 210.895 us; speedup vs baseline: 1.4842x; 1.4842x over previous
//
#include <hip/hip_runtime.h>

#define NB   4
#define H_IN 14
#define W_IN 14
#define FIN  32
#define DI   8
#define F    32
#define C    288   // 3*3*32
#define DO   16
#define HO   12
#define WO   12
#define NPOS (NB*HO*WO)   // 576
#define EPS  1e-7f

#define CH   16            // c-chunks for kern1/kern2
#define CC   (C/CH)        // 18

#define W2_BYTES   ((size_t)F*C*DO*DI*4)       // 4,718,592
#define CENT_BYTES ((size_t)NPOS*F*DO*4)       // 1,179,648
#define PART_BYTES ((size_t)CH*CENT_BYTES)     // 18,874,368 (part1; part2 aliases it)
#define OUT1_BYTES CENT_BYTES

__device__ __forceinline__ float dot8f(const float4 w0, const float4 w1,
                                       const float4 p0, const float4 p1) {
    return w0.x*p0.x + w0.y*p0.y + w0.z*p0.z + w0.w*p0.w
         + w1.x*p1.x + w1.y*p1.y + w1.z*p1.z + w1.w*p1.w;
}

// ---- transpose W[f][c][o][i] -> W2[c][o][f][i] --------------------------------
__global__ __launch_bounds__(256) void kernT(const float* __restrict__ Wt,
                                             float* __restrict__ W2) {
    const int idx4 = blockIdx.x*256 + threadIdx.x;   // output float4 index
    const int i2 = idx4 & 1;
    const int f  = (idx4 >> 1) & 31;
    const int o  = (idx4 >> 6) & 15;
    const int c  = idx4 >> 10;
    ((float4*)W2)[idx4] = ((const float4*)Wt)[((size_t)(f*C + c)*DO + o)*2 + i2];
}

// ---- kern1: cent1 partials. thread=(f, o-pair), loops 8 positions. ------------
// writes part1[ch][pos][o][f] (coalesced dword stores over f)
__global__ __launch_bounds__(256, 4) void kern1n(const float* __restrict__ x,
                                                 const float* __restrict__ W2,
                                                 float* __restrict__ part1)
{
    const int tid = threadIdx.x;
    const int f  = tid & 31;
    const int og = tid >> 5;          // 0..7
    const int o0 = 2*og, o1 = o0 + 1;
    const int ch = blockIdx.x & (CH-1);
    const int pg = blockIdx.x >> 4;   // 0..71

    int baseoff[8];
    #pragma unroll
    for (int p = 0; p < 8; ++p) {
        const int pos = pg*8 + p;
        const int b = pos/(HO*WO), rem = pos%(HO*WO), ho = rem/WO, wo = rem%WO;
        baseoff[p] = ((b*H_IN + ho)*W_IN + wo)*FIN*DI;
    }

    const float4* W2f4 = (const float4*)W2;
    float acc0[8], acc1[8];
    #pragma unroll
    for (int p = 0; p < 8; ++p) { acc0[p] = 0.f; acc1[p] = 0.f; }

    const int c0 = ch*CC;
    #pragma unroll 1
    for (int c = c0; c < c0 + CC; ++c) {
        const int slab = c >> 5, fin = c & 31;
        const int kh = slab/3, kw = slab%3;
        const int coff = (kh*W_IN + kw)*FIN*DI + fin*DI;
        const float4* wp = W2f4 + (size_t)c*1024 + f*2;
        const float4 w00 = wp[o0*64], w01 = wp[o0*64 + 1];
        const float4 w10 = wp[o1*64], w11 = wp[o1*64 + 1];
        #pragma unroll
        for (int p = 0; p < 8; ++p) {
            const float4* px = (const float4*)(x + baseoff[p] + coff);
            const float4 a = px[0], bq = px[1];
            acc0[p] += dot8f(w00, w01, a, bq);
            acc1[p] += dot8f(w10, w11, a, bq);
        }
    }
    #pragma unroll
    for (int p = 0; p < 8; ++p) {
        const size_t base = ((size_t)(ch*NPOS + pg*8 + p))*DO;
        part1[(base + o0)*F + f] = acc0[p];
        part1[(base + o1)*F + f] = acc1[p];
    }
}

// ---- kernO: out1[pos][f][o] = squash(sum_ch part1 / 32). 576 x 512 threads. ---
__global__ __launch_bounds__(512) void kernO(const float* __restrict__ part1,
                                             float* __restrict__ out1)
{
    __shared__ float red[512];
    const int pos = blockIdx.x, tid = threadIdx.x;
    const int f = tid & 31, o = tid >> 5;

    float s = 0.f;
    #pragma unroll
    for (int k = 0; k < CH; ++k)
        s += part1[(size_t)(k*NPOS + pos)*512 + tid];
    s *= (1.f/32.f);

    red[tid] = s*s;
    __syncthreads();
    if (tid < 256) red[tid] += red[tid + 256];
    __syncthreads();
    if (tid < 128) red[tid] += red[tid + 128];
    __syncthreads();
    if (tid < 64)  red[tid] += red[tid + 64];
    __syncthreads();
    if (tid < 32) {
        const float sn = red[tid] + red[tid + 32];
        red[tid] = (sn/(1.f + sn)) * rsqrtf(sn + EPS);
    }
    __syncthreads();
    out1[(size_t)pos*512 + f*DO + o] = s * red[f];
}

// ---- kern2: thread=(f,pp) handles positions posA, posB=posA+8. ----------------
// reads out1 buffer; writes part2[ch][pos][f][o] (float4). part2 aliases part1.
__global__ __launch_bounds__(256, 3) void kern2n(const float* __restrict__ x,
                                                 const float* __restrict__ W2,
                                                 const float* __restrict__ out1,
                                                 float* __restrict__ part2)
{
    const int tid = threadIdx.x;
    const int f  = tid & 31;
    const int pp = tid >> 5;          // 0..7
    const int ch = blockIdx.x & (CH-1);
    const int pg = blockIdx.x >> 4;   // 0..35
    const int posA = pg*16 + pp, posB = posA + 8;

    int baseA, baseB;
    {
        int b = posA/(HO*WO), rem = posA%(HO*WO), ho = rem/WO, wo = rem%WO;
        baseA = ((b*H_IN + ho)*W_IN + wo)*FIN*DI;
        b = posB/(HO*WO); rem = posB%(HO*WO); ho = rem/WO; wo = rem%WO;
        baseB = ((b*H_IN + ho)*W_IN + wo)*FIN*DI;
    }

    float o1A[DO], o1B[DO];
    {
        const float4* sA = (const float4*)(out1 + (size_t)posA*512 + f*DO);
        const float4* sB = (const float4*)(out1 + (size_t)posB*512 + f*DO);
        #pragma unroll
        for (int q = 0; q < 4; ++q) {
            const float4 va = sA[q], vb = sB[q];
            o1A[4*q+0] = va.x; o1A[4*q+1] = va.y; o1A[4*q+2] = va.z; o1A[4*q+3] = va.w;
            o1B[4*q+0] = vb.x; o1B[4*q+1] = vb.y; o1B[4*q+2] = vb.z; o1B[4*q+3] = vb.w;
        }
    }

    const float4* W2f4 = (const float4*)W2;
    float accA[DO], accB[DO];
    #pragma unroll
    for (int o = 0; o < DO; ++o) { accA[o] = 0.f; accB[o] = 0.f; }

    const int c0 = ch*CC;
    #pragma unroll 1
    for (int c = c0; c < c0 + CC; ++c) {
        const int slab = c >> 5, fin = c & 31;
        const int kh = slab/3, kw = slab%3;
        const int coff = (kh*W_IN + kw)*FIN*DI + fin*DI;
        const float4* pxA = (const float4*)(x + baseA + coff);
        const float4* pxB = (const float4*)(x + baseB + coff);
        const float4 a0 = pxA[0], a1 = pxA[1];
        const float4 b0 = pxB[0], b1 = pxB[1];
        const float4* wb = W2f4 + (size_t)c*1024 + f*2;

        float predA[DO], predB[DO];
        {   // o = 0..7
            float4 w[16];
            #pragma unroll
            for (int o = 0; o < 8; ++o) { w[2*o] = wb[o*64]; w[2*o+1] = wb[o*64+1]; }
            #pragma unroll
            for (int o = 0; o < 8; ++o) {
                predA[o] = dot8f(w[2*o], w[2*o+1], a0, a1);
                predB[o] = dot8f(w[2*o], w[2*o+1], b0, b1);
            }
        }
        {   // o = 8..15
            float4 w[16];
            #pragma unroll
            for (int o = 0; o < 8; ++o) { w[2*o] = wb[(o+8)*64]; w[2*o+1] = wb[(o+8)*64+1]; }
            #pragma unroll
            for (int o = 0; o < 8; ++o) {
                predA[8+o] = dot8f(w[2*o], w[2*o+1], a0, a1);
                predB[8+o] = dot8f(w[2*o], w[2*o+1], b0, b1);
            }
        }

        float agrA = 0.f, agrB = 0.f;
        #pragma unroll
        for (int o = 0; o < DO; ++o) { agrA += predA[o]*o1A[o]; agrB += predB[o]*o1B[o]; }

        // softmax over the 32 f-lanes (xor masks <32 stay within each half-wave)
        float mA = agrA, mB = agrB;
        mA = fmaxf(mA, __shfl_xor(mA, 1));  mB = fmaxf(mB, __shfl_xor(mB, 1));
        mA = fmaxf(mA, __shfl_xor(mA, 2));  mB = fmaxf(mB, __shfl_xor(mB, 2));
        mA = fmaxf(mA, __shfl_xor(mA, 4));  mB = fmaxf(mB, __shfl_xor(mB, 4));
        mA = fmaxf(mA, __shfl_xor(mA, 8));  mB = fmaxf(mB, __shfl_xor(mB, 8));
        mA = fmaxf(mA, __shfl_xor(mA, 16)); mB = fmaxf(mB, __shfl_xor(mB, 16));
        const float eA = __expf(agrA - mA), eB = __expf(agrB - mB);
        float sA = eA, sB = eB;
        sA += __shfl_xor(sA, 1);  sB += __shfl_xor(sB, 1);
        sA += __shfl_xor(sA, 2);  sB += __shfl_xor(sB, 2);
        sA += __shfl_xor(sA, 4);  sB += __shfl_xor(sB, 4);
        sA += __shfl_xor(sA, 8);  sB += __shfl_xor(sB, 8);
        sA += __shfl_xor(sA, 16); sB += __shfl_xor(sB, 16);
        const float ccA = eA / sA, ccB = eB / sB;

        #pragma unroll
        for (int o = 0; o < DO; ++o) { accA[o] += ccA*predA[o]; accB[o] += ccB*predB[o]; }
    }

    float4* dA = (float4*)(part2 + ((size_t)(ch*NPOS + posA)*F + f)*DO);
    dA[0] = make_float4(accA[0],  accA[1],  accA[2],  accA[3]);
    dA[1] = make_float4(accA[4],  accA[5],  accA[6],  accA[7]);
    dA[2] = make_float4(accA[8],  accA[9],  accA[10], accA[11]);
    dA[3] = make_float4(accA[12], accA[13], accA[14], accA[15]);
    float4* dB = (float4*)(part2 + ((size_t)(ch*NPOS + posB)*F + f)*DO);
    dB[0] = make_float4(accB[0],  accB[1],  accB[2],  accB[3]);
    dB[1] = make_float4(accB[4],  accB[5],  accB[6],  accB[7]);
    dB[2] = make_float4(accB[8],  accB[9],  accB[10], accB[11]);
    dB[3] = make_float4(accB[12], accB[13], accB[14], accB[15]);
}

// ---- kern3: reduce cent2 partials, squash, store. -----------------------------
__global__ __launch_bounds__(256) void kern3(const float* __restrict__ part2,
                                             float* __restrict__ out)
{
    const int tid = threadIdx.x;
    const int f = tid & 31, p = tid >> 5;
    const int pos = blockIdx.x*8 + p;

    float cent[DO];
    #pragma unroll
    for (int o = 0; o < DO; ++o) cent[o] = 0.f;
    #pragma unroll
    for (int k = 0; k < CH; ++k) {
        const float4* s = (const float4*)(part2 + ((size_t)(k*NPOS + pos)*F + f)*DO);
        #pragma unroll
        for (int q = 0; q < 4; ++q) {
            const float4 v = s[q];
            cent[q*4+0] += v.x; cent[q*4+1] += v.y;
            cent[q*4+2] += v.z; cent[q*4+3] += v.w;
        }
    }
    float sn = 0.f;
    #pragma unroll
    for (int o = 0; o < DO; ++o) sn += cent[o]*cent[o];
    const float sc = (sn/(1.f + sn)) * rsqrtf(sn + EPS);
    float4* dst = (float4*)(out + ((size_t)pos*F + f)*DO);
    dst[0] = make_float4(cent[0]*sc,  cent[1]*sc,  cent[2]*sc,  cent[3]*sc);
    dst[1] = make_float4(cent[4]*sc,  cent[5]*sc,  cent[6]*sc,  cent[7]*sc);
    dst[2] = make_float4(cent[8]*sc,  cent[9]*sc,  cent[10]*sc, cent[11]*sc);
    dst[3] = make_float4(cent[12]*sc, cent[13]*sc, cent[14]*sc, cent[15]*sc);
}

// -------- fp32 single-kernel fallback (if ws too small) ------------------------
__device__ __forceinline__ float dot8(const float4* __restrict__ w,
                                      const float4 p0, const float4 p1) {
    float4 a = w[0], b = w[1];
    return a.x*p0.x + a.y*p0.y + a.z*p0.z + a.w*p0.w
         + b.x*p1.x + b.y*p1.y + b.z*p1.z + b.w*p1.w;
}

__global__ __launch_bounds__(256) void capsule_kernel_f32(
    const float* __restrict__ x, const float* __restrict__ Wt,
    float* __restrict__ out)
{
    __shared__ float patch[C*DI];
    __shared__ float cent[F*DO];
    __shared__ float out1[F*DO];
    __shared__ float agr[F*C];
    __shared__ float scale_s[F];

    const int tid = threadIdx.x;
    const int pos = blockIdx.x;
    const int b   = pos / (HO*WO);
    const int rem = pos % (HO*WO);
    const int ho  = rem / WO;
    const int wo  = rem % WO;

    #pragma unroll
    for (int slab = 0; slab < 9; ++slab) {
        const int kh = slab / 3, kw = slab % 3;
        const float* src = x + (((b*H_IN + ho + kh)*W_IN + (wo + kw))*FIN)*DI;
        patch[slab*256 + tid] = src[tid];
    }
    __syncthreads();

    const float4* pv = (const float4*)patch;

    {
        const int fo0 = tid, fo1 = tid + 256;
        const int f0 = fo0 >> 4, o0 = fo0 & 15;
        const int f1 = fo1 >> 4, o1 = fo1 & 15;
        float acc0 = 0.f, acc1 = 0.f;
        for (int c = 0; c < C; ++c) {
            const float4 p0 = pv[c*2], p1 = pv[c*2+1];
            acc0 += dot8((const float4*)(Wt + ((f0*C + c)*DO + o0)*DI), p0, p1);
            acc1 += dot8((const float4*)(Wt + ((f1*C + c)*DO + o1)*DI), p0, p1);
        }
        cent[fo0] = acc0 * (1.f/32.f);
        cent[fo1] = acc1 * (1.f/32.f);
    }
    __syncthreads();

    if (tid < F) {
        float sn = 0.f;
        #pragma unroll
        for (int o = 0; o < DO; ++o) { float v = cent[tid*DO + o]; sn += v*v; }
        const float sc = (sn/(1.f + sn)) * rsqrtf(sn + EPS);
        #pragma unroll
        for (int o = 0; o < DO; ++o) out1[tid*DO + o] = cent[tid*DO + o] * sc;
    }
    __syncthreads();

    #pragma unroll 1
    for (int r = 0; r < (F*C)/256; ++r) {
        const int pp = tid + 256*r;
        const int f = pp / C, c = pp % C;
        const float4* wrow = (const float4*)(Wt + (f*C + c)*DO*DI);
        const float4 p0 = pv[c*2], p1 = pv[c*2+1];
        float a = 0.f;
        #pragma unroll
        for (int o = 0; o < DO; ++o) a += dot8(wrow + o*2, p0, p1) * out1[f*DO + o];
        agr[pp] = a;
    }
    __syncthreads();

    for (int c = tid; c < C; c += 256) {
        float m = -1e30f;
        #pragma unroll
        for (int f = 0; f < F; ++f) m = fmaxf(m, agr[f*C + c]);
        float s = 0.f;
        #pragma unroll
        for (int f = 0; f < F; ++f) {
            const float e = __expf(agr[f*C + c] - m);
            agr[f*C + c] = e; s += e;
        }
        const float inv = 1.f / s;
        #pragma unroll
        for (int f = 0; f < F; ++f) agr[f*C + c] *= inv;
    }
    __syncthreads();

    {
        const int fo0 = tid, fo1 = tid + 256;
        const int f0 = fo0 >> 4, o0 = fo0 & 15;
        const int f1 = fo1 >> 4, o1 = fo1 & 15;
        float acc0 = 0.f, acc1 = 0.f;
        for (int c = 0; c < C; ++c) {
            const float4 p0 = pv[c*2], p1 = pv[c*2+1];
            acc0 += agr[f0*C + c] * dot8((const float4*)(Wt + ((f0*C + c)*DO + o0)*DI), p0, p1);
            acc1 += agr[f1*C + c] * dot8((const float4*)(Wt + ((f1*C + c)*DO + o1)*DI), p0, p1);
        }
        cent[fo0] = acc0;
        cent[fo1] = acc1;
    }
    __syncthreads();

    if (tid < F) {
        float sn = 0.f;
        #pragma unroll
        for (int o = 0; o < DO; ++o) { float v = cent[tid*DO + o]; sn += v*v; }
        scale_s[tid] = (sn/(1.f + sn)) * rsqrtf(sn + EPS);
    }
    __syncthreads();

    out[pos*(F*DO) + tid]       = cent[tid]       * scale_s[tid >> 4];
    out[pos*(F*DO) + tid + 256] = cent[tid + 256] * scale_s[(tid >> 4) + 16];
}

extern "C" void kernel_launch(void* const* d_in, const int* in_sizes, int n_in,
                              void* d_out, int out_size, void* d_ws, size_t ws_size,
                              hipStream_t stream) {
    const float* x  = (const float*)d_in[0];
    const float* Wt = (const float*)d_in[1];
    float* out = (float*)d_out;

    if (ws_size >= W2_BYTES + PART_BYTES + OUT1_BYTES) {
        float* W2    = (float*)d_ws;
        float* part1 = (float*)((char*)d_ws + W2_BYTES);      // part2 aliases part1
        float* out1  = (float*)((char*)d_ws + W2_BYTES + PART_BYTES);
        kernT<<<(F*C*DO*DI)/4/256, 256, 0, stream>>>(Wt, W2);       // 1152 blocks
        kern1n<<<CH*(NPOS/8), 256, 0, stream>>>(x, W2, part1);      // 1152 blocks
        kernO<<<NPOS, 512, 0, stream>>>(part1, out1);               // 576 blocks
        kern2n<<<CH*(NPOS/16), 256, 0, stream>>>(x, W2, out1, part1); // 576 blocks
        kern3<<<NPOS/8, 256, 0, stream>>>(part1, out);              // 72 blocks
    } else {
        capsule_kernel_f32<<<NPOS, 256, 0, stream>>>(x, Wt, out);
    }
}